// Round 20
// baseline (751.292 us; speedup 1.0000x reference)
//
#include <hip/hip_runtime.h>

typedef _Float16 f16;
typedef _Float16 f16x2 __attribute__((ext_vector_type(2)));
typedef _Float16 f16x4 __attribute__((ext_vector_type(4)));
typedef _Float16 f16x8 __attribute__((ext_vector_type(8)));
typedef float f32x4 __attribute__((ext_vector_type(4)));

#define QSCALE 0.08838834764831845f  // DK^-0.5

#define RAW_BARRIER() do { \
    asm volatile("s_waitcnt lgkmcnt(0)" ::: "memory"); \
    __builtin_amdgcn_s_barrier(); \
    __builtin_amdgcn_sched_barrier(0); \
} while (0)

// ------------------------------------------------------------------
// transpose fp32 [R][C] -> f16 [C][R]
// ------------------------------------------------------------------
__global__ __launch_bounds__(256) void transpose16_kernel(const float* __restrict__ in,
                                                          f16* __restrict__ out, int R, int C) {
    __shared__ f16 tile[64][66];
    int c0 = blockIdx.x * 64, r0 = blockIdx.y * 64;
    int tid = threadIdx.x;
#pragma unroll
    for (int i = 0; i < 16; ++i) {
        int idx = i * 256 + tid;
        int r = idx >> 6, c = idx & 63;
        tile[r][c] = (f16)in[(long)(r0 + r) * C + (c0 + c)];
    }
    __syncthreads();
#pragma unroll
    for (int i = 0; i < 16; ++i) {
        int idx = i * 256 + tid;
        int orow = idx >> 6, oc = idx & 63;
        out[(long)(c0 + orow) * R + (r0 + oc)] = tile[oc][orow];
    }
}

// ------------------------------------------------------------------
// 256xBN deep-pipelined f16 MFMA GEMM. BN = 64*NJ.
// r16 schedule (measured best). AF32: A is fp32, converted in commit
// (fuses the old cvt16 kernel; bit-identical rounding).
// ------------------------------------------------------------------
template <int NJ, int F16OUT, int AF32>
__global__ __launch_bounds__(512, 1) void gemm256_kernel(const void* __restrict__ Av,
                                                         const f16* __restrict__ Bt,
                                                         void* __restrict__ Cout,
                                                         int M, int N, int Kd) {
    constexpr int BN = 64 * NJ;
    constexpr int BNW = 16 * NJ;
    __shared__ f16 sA[2][256 * 64];
    __shared__ f16 sB[2][BN * 64];
    const f16* A16 = (const f16*)Av;
    const float* A32 = (const float*)Av;
    const int tid = threadIdx.x;
    const int lane = tid & 63, wv = tid >> 6;
    const int wm = wv >> 2, wn = wv & 3;
    const int m0 = blockIdx.y * 256, n0 = blockIdx.x * BN;
    const int lrow = lane & 15, lk = lane >> 4;
    const int nK = Kd >> 6;

    f32x4 acc[8][NJ] = {};
    f32x4 ra[4];        // f16 path staging
    f32x4 ra32[4][2];   // fp32 path staging
    f32x4 rb[NJ];

    auto issue = [&](int k0) {
#pragma unroll
        for (int j = 0; j < 4; ++j) {
            int P = (tid + j * 512) * 16;
            int row = P >> 7;
            int koff = (P & 127) >> 1;  // f16-elem offset == f32-elem offset
            if (AF32) {
                const float* ga = A32 + (long)(m0 + row) * Kd + k0 + koff;
                ra32[j][0] = *(const f32x4*)ga;
                ra32[j][1] = *(const f32x4*)(ga + 4);
            } else {
                ra[j] = *(const f32x4*)(A16 + (long)(m0 + row) * Kd + k0 + koff);
            }
        }
#pragma unroll
        for (int j = 0; j < NJ; ++j) {
            int P = (tid + j * 512) * 16;
            int row = P >> 7;
            int koff = (P & 127) >> 1;
            rb[j] = *(const f32x4*)(Bt + (long)(n0 + row) * Kd + k0 + koff);
        }
    };
    auto commit = [&](int buf) {
#pragma unroll
        for (int j = 0; j < 4; ++j) {
            int P = (tid + j * 512) * 16;
            int row = P >> 7;
            int sw = P ^ ((row & 7) << 4);
            if (AF32) {
                f16x8 h;
#pragma unroll
                for (int e = 0; e < 4; ++e) {
                    h[e] = (f16)ra32[j][0][e];
                    h[4 + e] = (f16)ra32[j][1][e];
                }
                *(f16x8*)((char*)&sA[buf][0] + sw) = h;
            } else {
                *(f32x4*)((char*)&sA[buf][0] + sw) = ra[j];
            }
        }
#pragma unroll
        for (int j = 0; j < NJ; ++j) {
            int P = (tid + j * 512) * 16;
            int row = P >> 7;
            int sw = P ^ ((row & 7) << 4);
            *(f32x4*)((char*)&sB[buf][0] + sw) = rb[j];
        }
    };

    issue(0);
    commit(0);
    if (nK > 1) issue(64);
    RAW_BARRIER();

    int cur = 0;
    for (int t = 0; t < nK; ++t) {
        if (t + 1 < nK) commit(cur ^ 1);
        if (t + 2 < nK) issue((t + 2) * 64);
        const char* bA = (const char*)&sA[cur][0];
        const char* bB = (const char*)&sB[cur][0];
        __builtin_amdgcn_s_setprio(1);
#pragma unroll
        for (int kk = 0; kk < 2; ++kk) {
            f16x8 bf[NJ];
#pragma unroll
            for (int j = 0; j < NJ; ++j) {
                int brow = wn * BNW + j * 16 + lrow;
                int bbyte = brow * 128 + kk * 64 + lk * 16;
                bf[j] = *(const f16x8*)(bB + (bbyte ^ ((brow & 7) << 4)));
            }
#pragma unroll
            for (int i = 0; i < 8; ++i) {
                int arow = wm * 128 + i * 16 + lrow;
                int abyte = arow * 128 + kk * 64 + lk * 16;
                f16x8 af = *(const f16x8*)(bA + (abyte ^ ((arow & 7) << 4)));
#pragma unroll
                for (int j = 0; j < NJ; ++j)
                    acc[i][j] = __builtin_amdgcn_mfma_f32_16x16x32_f16(af, bf[j], acc[i][j], 0, 0, 0);
            }
        }
        __builtin_amdgcn_s_setprio(0);
        RAW_BARRIER();
        cur ^= 1;
    }

#pragma unroll
    for (int i = 0; i < 8; ++i) {
        int gm_base = m0 + wm * 128 + i * 16 + lk * 4;
#pragma unroll
        for (int j = 0; j < NJ; ++j) {
            int gn = n0 + wn * BNW + j * 16 + lrow;
#pragma unroll
            for (int r = 0; r < 4; ++r) {
                long idx = (long)(gm_base + r) * N + gn;
                if (F16OUT) ((f16*)Cout)[idx] = (f16)acc[i][j][r];
                else        ((float*)Cout)[idx] = acc[i][j][r];
            }
        }
    }
}

// ------------------------------------------------------------------
// ba = x @ w_ba, FUSED g/beta epilogue (r17, 4 blocks/CU — proven).
// ------------------------------------------------------------------
__global__ __launch_bounds__(256) void ba_gemm_kernel(const float* __restrict__ x,
                                                      const float* __restrict__ w,
                                                      const float* __restrict__ a_log,
                                                      const float* __restrict__ dt_bias,
                                                      float* __restrict__ gout,
                                                      float* __restrict__ bt) {
    __shared__ float xs[4][2048];
    int tid = threadIdx.x;
    int t0 = blockIdx.x * 4;
    int o = tid & 63, tg = tid >> 6;
    for (int i = tid; i < 4 * 512; i += 256) {
        int tok = i >> 9, kq = i & 511;
        ((f32x4*)&xs[tok][0])[kq] = ((const f32x4*)(x + (long)(t0 + tok) * 2048))[kq];
    }
    __syncthreads();
    const float* xr = &xs[tg][0];
    float acc = 0.f;
    for (int k = 0; k < 2048; ++k)
        acc = fmaf(xr[k], w[(long)k * 64 + o], acc);

    int hv = ((o >> 2) << 1) | (o & 1);
    bool isB = (o & 2) == 0;
    int tok = t0 + tg;
    int b = tok >> 11, s = tok & 2047;
    long oidx = ((long)b * 32 + hv) * 2048 + s;
    if (isB) {
        bt[oidx] = 1.f / (1.f + expf(-acc));
    } else {
        float xx = acc + dt_bias[hv];
        float sp = (xx > 20.f) ? xx : log1pf(expf(xx));
        gout[oidx] = -expf(a_log[hv]) * sp;
    }
}

// ------------------------------------------------------------------
// depthwise causal conv(K=4) + bias + SiLU (+ L2norm for q/k heads)
// k-head blocks ALSO emit the transposed copy khT.
// ------------------------------------------------------------------
__global__ __launch_bounds__(256) void conv_kernel(const f16* __restrict__ qkvz,
                                                   const float* __restrict__ cw,
                                                   const float* __restrict__ cb,
                                                   f16* __restrict__ qh,
                                                   f16* __restrict__ kh,
                                                   f16* __restrict__ vh,
                                                   f16* __restrict__ khT) {
    __shared__ float Lin[35 * 128];
    __shared__ float Lout[32 * 128];
    __shared__ float Lsc[32];
    int g = blockIdx.x;
    int s0 = blockIdx.y * 32;
    int b = blockIdx.z;
    int tid = threadIdx.x;
    int colbase, chbase;
    f16* outp;
    bool donorm;
    bool isk = false;
    int hk = 0;
    float nmul;
    if (g < 16) {
        colbase = g * 768; chbase = g * 128;
        outp = qh + (((long)b * 16 + g) * 2048 + s0) * 128;
        donorm = true; nmul = QSCALE;
    } else if (g < 32) {
        hk = g - 16;
        colbase = hk * 768 + 128; chbase = 2048 + hk * 128;
        outp = kh + (((long)b * 16 + hk) * 2048 + s0) * 128;
        donorm = true; nmul = 1.f; isk = true;
    } else {
        int hv = g - 32;
        colbase = (hv >> 1) * 768 + 256 + (hv & 1) * 128; chbase = 4096 + hv * 128;
        outp = vh + (((long)b * 32 + hv) * 2048 + s0) * 128;
        donorm = false; nmul = 1.f;
    }
    for (int ci = tid; ci < 35 * 16; ci += 256) {
        int sr = ci >> 4, cc = (ci & 15) * 8;
        int s = s0 + sr - 3;
        f32x4 lo = {}, hi = {};
        if (s >= 0) {
            f16x8 v = *(const f16x8*)(qkvz + ((long)b * 2048 + s) * 12288 + colbase + cc);
#pragma unroll
            for (int e = 0; e < 4; ++e) { lo[e] = (float)v[e]; hi[e] = (float)v[4 + e]; }
        }
        *(f32x4*)&Lin[sr * 128 + cc] = lo;
        *(f32x4*)&Lin[sr * 128 + cc + 4] = hi;
    }
    __syncthreads();
    int c = tid & 127, sg = tid >> 7;
    float w0 = cw[(chbase + c) * 4 + 0];
    float w1 = cw[(chbase + c) * 4 + 1];
    float w2 = cw[(chbase + c) * 4 + 2];
    float w3 = cw[(chbase + c) * 4 + 3];
    float bias = cb[chbase + c];
#pragma unroll
    for (int j = 0; j < 16; ++j) {
        int sl = sg * 16 + j;
        float v = w0 * Lin[sl * 128 + c] + w1 * Lin[(sl + 1) * 128 + c] +
                  w2 * Lin[(sl + 2) * 128 + c] + w3 * Lin[(sl + 3) * 128 + c] + bias;
        v = v / (1.f + expf(-v));  // SiLU
        Lout[sl * 128 + c] = v;
    }
    __syncthreads();
    if (donorm) {
        int token = tid >> 3, part = tid & 7;
        float ss = 0.f;
#pragma unroll
        for (int i = 0; i < 16; ++i) {
            float v = Lout[token * 128 + part * 16 + i];
            ss += v * v;
        }
        ss += __shfl_xor(ss, 1); ss += __shfl_xor(ss, 2); ss += __shfl_xor(ss, 4);
        if (part == 0) Lsc[token] = rsqrtf(ss + 1e-6f) * nmul;
        __syncthreads();
#pragma unroll
        for (int j = 0; j < 16; ++j) {
            int sl = sg * 16 + j;
            outp[(long)sl * 128 + c] = (f16)(Lout[sl * 128 + c] * Lsc[sl]);
        }
        if (isk) {
            int dk = tid >> 1, sh = tid & 1;
            f16x8 v0, v1;
#pragma unroll
            for (int i = 0; i < 8; ++i) {
                v0[i] = (f16)(Lout[(sh * 16 + i) * 128 + dk] * Lsc[sh * 16 + i]);
                v1[i] = (f16)(Lout[(sh * 16 + 8 + i) * 128 + dk] * Lsc[sh * 16 + 8 + i]);
            }
            f16* kt = khT + ((long)(b * 16 + hk) * 128 + dk) * 2048 + s0 + sh * 16;
            *(f16x8*)kt = v0;
            *(f16x8*)(kt + 8) = v1;
        }
    } else {
#pragma unroll
        for (int j = 0; j < 16; ++j) {
            int sl = sg * 16 + j;
            outp[(long)sl * 128 + c] = (f16)Lout[sl * 128 + c];
        }
    }
}

// ------------------------------------------------------------------
// chunk_pre: per (b,hv,chunk of 32) — one wave. (r15/r17, proven)
// ------------------------------------------------------------------
__global__ __launch_bounds__(64) void chunk_pre_kernel(const f16* __restrict__ qh,
                                                       const f16* __restrict__ kh,
                                                       const f16* __restrict__ vh,
                                                       const float* __restrict__ gb,
                                                       const float* __restrict__ bt,
                                                       f16* __restrict__ Wg,
                                                       f16* __restrict__ T2ng,
                                                       f16* __restrict__ d0g,
                                                       float* __restrict__ pvg) {
    __shared__ f16 VTl[128 * 32];
    __shared__ float KKl[32 * 32];
    __shared__ float RL[32 * 32];
    __shared__ float Tf[32 * 33];
    __shared__ f16 Tl[32 * 64];
    __shared__ float cuml[32], bl[32], pl[32];

    int bid = blockIdx.x;
    int chunk = bid & 63;
    int hv = (bid >> 6) & 31;
    int b = bid >> 11;
    int bh = b * 16 + (hv >> 1);
    int l = threadIdx.x;
    int h = l >> 4, c = l & 15;
    long chid = bid;

    const f16* kbase = kh + ((long)bh * 2048 + chunk * 32) * 128;
    const f16* qbase = qh + ((long)bh * 2048 + chunk * 32) * 128;
    const f16* vbase = vh + (((long)b * 32 + hv) * 2048 + chunk * 32) * 128;
    const float* gp = gb + ((long)b * 32 + hv) * 2048 + chunk * 32;
    const float* bp = bt + ((long)b * 32 + hv) * 2048 + chunk * 32;

    f16x8 fk[2][4], fq[2][4];
#pragma unroll
    for (int ti = 0; ti < 2; ++ti)
#pragma unroll
        for (int kk = 0; kk < 4; ++kk) {
            fk[ti][kk] = *(const f16x8*)(kbase + (c + 16 * ti) * 128 + kk * 32 + h * 8);
            fq[ti][kk] = *(const f16x8*)(qbase + (c + 16 * ti) * 128 + kk * 32 + h * 8);
        }

    float gv = (l < 32) ? gp[l] : 0.f;
#pragma unroll
    for (int d = 1; d < 32; d <<= 1) {
        float t2 = __shfl_up(gv, d);
        if (l >= d) gv += t2;
    }
    if (l < 32) { cuml[l] = gv; bl[l] = bp[l]; pl[l] = expf(gv); }
    __syncthreads();

#pragma unroll
    for (int it = 0; it < 8; ++it) {
        int idx = (l + it * 64) * 8;
        int row = idx >> 7, col = idx & 127;
        f16x8 v = *(const f16x8*)(vbase + (long)row * 128 + col);
        float be = bl[row];
#pragma unroll
        for (int e = 0; e < 8; ++e) {
            int dv = col + e;
            int byte = (dv * 64 + row * 2) ^ ((dv & 3) << 4);
            *(f16*)((char*)VTl + byte) = (f16)((float)v[e] * be);
        }
    }
#pragma unroll
    for (int it = 0; it < 16; ++it) {
        int e = l * 16 + it;
        int i = e >> 5, j = e & 31;
        RL[e] = (j <= i) ? expf(cuml[i] - cuml[j]) : 0.f;
    }
    __syncthreads();

    {
        f32x4 acc[2][2] = {};
#pragma unroll
        for (int kk = 0; kk < 4; ++kk) {
            acc[0][0] = __builtin_amdgcn_mfma_f32_16x16x32_f16(fk[0][kk], fk[0][kk], acc[0][0], 0, 0, 0);
            acc[0][1] = __builtin_amdgcn_mfma_f32_16x16x32_f16(fk[0][kk], fk[1][kk], acc[0][1], 0, 0, 0);
            acc[1][0] = __builtin_amdgcn_mfma_f32_16x16x32_f16(fk[1][kk], fk[0][kk], acc[1][0], 0, 0, 0);
            acc[1][1] = __builtin_amdgcn_mfma_f32_16x16x32_f16(fk[1][kk], fk[1][kk], acc[1][1], 0, 0, 0);
        }
#pragma unroll
        for (int ti = 0; ti < 2; ++ti)
#pragma unroll
            for (int tj = 0; tj < 2; ++tj)
#pragma unroll
                for (int r = 0; r < 4; ++r)
                    KKl[(h * 4 + r + 16 * ti) * 32 + c + 16 * tj] = acc[ti][tj][r];
    }
    {
        f32x4 acc[2][2] = {};
#pragma unroll
        for (int kk = 0; kk < 4; ++kk) {
            acc[0][0] = __builtin_amdgcn_mfma_f32_16x16x32_f16(fq[0][kk], fk[0][kk], acc[0][0], 0, 0, 0);
            acc[0][1] = __builtin_amdgcn_mfma_f32_16x16x32_f16(fq[0][kk], fk[1][kk], acc[0][1], 0, 0, 0);
            acc[1][0] = __builtin_amdgcn_mfma_f32_16x16x32_f16(fq[1][kk], fk[0][kk], acc[1][0], 0, 0, 0);
            acc[1][1] = __builtin_amdgcn_mfma_f32_16x16x32_f16(fq[1][kk], fk[1][kk], acc[1][1], 0, 0, 0);
        }
        __syncthreads();
#pragma unroll
        for (int ti = 0; ti < 2; ++ti)
#pragma unroll
            for (int tj = 0; tj < 2; ++tj)
#pragma unroll
                for (int r = 0; r < 4; ++r) {
                    int i = h * 4 + r + 16 * ti, j = c + 16 * tj;
                    Wg[chid * 1024 + i * 32 + j] = (f16)(acc[ti][tj][r] * RL[i * 32 + j]);
                }
    }

    if (l < 32) {
        int j = l;
        for (int i = 0; i < 32; ++i) {
            float s = (i == j) ? 1.f : 0.f;
            float bi = bl[i];
            for (int ll = j; ll < i; ++ll)
                s -= bi * KKl[i * 32 + ll] * RL[i * 32 + ll] * Tf[ll * 33 + j];
            Tf[i * 33 + j] = s;
        }
        float bpj = bl[j] * pl[j];
        for (int i = 0; i < 32; ++i) {
            float tv = (i >= j) ? Tf[i * 33 + j] : 0.f;
            int byte = (i * 128 + j * 2) ^ ((i & 3) << 4);
            *(f16*)((char*)Tl + byte) = (f16)tv;
            T2ng[chid * 1024 + i * 32 + j] = (f16)(-tv * bpj);
        }
        pvg[chid * 64 + j] = pl[j];
        pvg[chid * 64 + 32 + j] = expf(cuml[31] - cuml[j]);
    }
    __syncthreads();

    {
        f16x8 fT[2];
#pragma unroll
        for (int ti = 0; ti < 2; ++ti) {
            int row = c + 16 * ti;
            fT[ti] = *(const f16x8*)((const char*)Tl + ((row * 128 + h * 16) ^ ((row & 3) << 4)));
        }
#pragma unroll
        for (int nj = 0; nj < 8; ++nj) {
            int dv = c + 16 * nj;
            f16x8 fv = *(const f16x8*)((const char*)VTl + ((dv * 64 + h * 16) ^ ((dv & 3) << 4)));
            f32x4 a0 = {}, a1 = {};
            a0 = __builtin_amdgcn_mfma_f32_16x16x32_f16(fT[0], fv, a0, 0, 0, 0);
            a1 = __builtin_amdgcn_mfma_f32_16x16x32_f16(fT[1], fv, a1, 0, 0, 0);
            f16x4 s0, s1;
#pragma unroll
            for (int r = 0; r < 4; ++r) { s0[r] = (f16)a0[r]; s1[r] = (f16)a1[r]; }
            *(f16x4*)(d0g + chid * 4096 + (long)dv * 32 + 4 * h) = s0;
            *(f16x4*)(d0g + chid * 4096 + (long)dv * 32 + 16 + 4 * h) = s1;
        }
    }
}

// ------------------------------------------------------------------
// sequential chunked scan: grid 512 = (b,hv,vs of 16 dv); 1 wave.
// 2-chunk register double-buffer (r16, proven).
// ------------------------------------------------------------------
struct CR {
    f16x8 fk[2][4], fq[2][4], fkt[8], fT[2], fW[2];
    f16x4 fd0[2];
    f32x4 pva, pvb, kwa, kwb;
    float pc;
};

__global__ __launch_bounds__(64, 1) void scan_kernel(const f16* __restrict__ qh,
                                                     const f16* __restrict__ kh,
                                                     const f16* __restrict__ khT,
                                                     const f16* __restrict__ Wg,
                                                     const f16* __restrict__ T2ng,
                                                     const f16* __restrict__ d0g,
                                                     const float* __restrict__ pvg,
                                                     f16* __restrict__ ob) {
    __shared__ f16 Sl[2][16 * 128];
    __shared__ f16 AKl[16 * 32];
    __shared__ f16 Dl[16 * 32];

    int pbid = blockIdx.x;
    int bid = (pbid & 7) * 64 + (pbid >> 3);
    int vs = bid & 7;
    int hv = (bid >> 3) & 31;
    int b = bid >> 8;
    int bh32 = b * 32 + hv;
    int bh = b * 16 + (hv >> 1);
    int l = threadIdx.x, h = l >> 4, c = l & 15;

    const f16* kb = kh + (long)bh * 2048 * 128;
    const f16* qb = qh + (long)bh * 2048 * 128;
    const f16* ktb = khT + (long)bh * 128 * 2048;

    f16x8 z = {};
#pragma unroll
    for (int it = 0; it < 4; ++it) *(f16x8*)((char*)Sl[0] + (l + it * 64) * 16) = z;

    int cur = 0;

    auto loadC = [&](CR& R, int ch) {
        long chid = (long)bh32 * 64 + ch;
#pragma unroll
        for (int ti = 0; ti < 2; ++ti) {
            long row = (long)ch * 32 + c + 16 * ti;
#pragma unroll
            for (int kk = 0; kk < 4; ++kk) {
                R.fk[ti][kk] = *(const f16x8*)(kb + row * 128 + kk * 32 + h * 8);
                R.fq[ti][kk] = *(const f16x8*)(qb + row * 128 + kk * 32 + h * 8);
            }
            R.fT[ti] = *(const f16x8*)(T2ng + chid * 1024 + (c + 16 * ti) * 32 + h * 8);
            R.fW[ti] = *(const f16x8*)(Wg + chid * 1024 + (c + 16 * ti) * 32 + h * 8);
        }
#pragma unroll
        for (int ti = 0; ti < 8; ++ti)
            R.fkt[ti] = *(const f16x8*)(ktb + (long)(c + 16 * ti) * 2048 + ch * 32 + h * 8);
#pragma unroll
        for (int ti = 0; ti < 2; ++ti)
            R.fd0[ti] = *(const f16x4*)(d0g + chid * 4096 +
                                        (long)(vs * 16 + c) * 32 + 16 * ti + 4 * h);
        R.pva = *(const f32x4*)(pvg + chid * 64 + 4 * h);
        R.pvb = *(const f32x4*)(pvg + chid * 64 + 16 + 4 * h);
        R.pc = pvg[chid * 64 + 31];
        R.kwa = *(const f32x4*)(pvg + chid * 64 + 32 + h * 8);
        R.kwb = *(const f32x4*)(pvg + chid * 64 + 36 + h * 8);
    };

    auto computeC = [&](const CR& R, int ch) {
        const int dv = c;
        f16x8 fS[4];
#pragma unroll
        for (int kk = 0; kk < 4; ++kk)
            fS[kk] = *(const f16x8*)((char*)Sl[cur] +
                                     (dv * 256 + ((kk * 64 + h * 16) ^ ((dv & 7) << 4))));
        f32x4 AK[2] = {}, AQ[2] = {};
#pragma unroll
        for (int ti = 0; ti < 2; ++ti)
#pragma unroll
            for (int kk = 0; kk < 4; ++kk) {
                AK[ti] = __builtin_amdgcn_mfma_f32_16x16x32_f16(R.fk[ti][kk], fS[kk], AK[ti], 0, 0, 0);
                AQ[ti] = __builtin_amdgcn_mfma_f32_16x16x32_f16(R.fq[ti][kk], fS[kk], AQ[ti], 0, 0, 0);
            }
#pragma unroll
        for (int ti = 0; ti < 2; ++ti) {
            f16x4 t;
#pragma unroll
            for (int r = 0; r < 4; ++r) t[r] = (f16)AK[ti][r];
            *(f16x4*)((char*)AKl + ((dv * 64 + 32 * ti + 8 * h) ^ ((dv & 3) << 4))) = t;
        }
        f32x4 Dv[2];
#pragma unroll
        for (int ti = 0; ti < 2; ++ti)
#pragma unroll
            for (int r = 0; r < 4; ++r) Dv[ti][r] = (float)R.fd0[ti][r];
        {
            f16x8 fak = *(const f16x8*)((char*)AKl + ((dv * 64 + h * 16) ^ ((dv & 3) << 4)));
#pragma unroll
            for (int ti = 0; ti < 2; ++ti)
                Dv[ti] = __builtin_amdgcn_mfma_f32_16x16x32_f16(R.fT[ti], fak, Dv[ti], 0, 0, 0);
        }
#pragma unroll
        for (int ti = 0; ti < 2; ++ti) {
            f16x4 t;
#pragma unroll
            for (int r = 0; r < 4; ++r) t[r] = (f16)Dv[ti][r];
            *(f16x4*)((char*)Dl + ((dv * 64 + 32 * ti + 8 * h) ^ ((dv & 3) << 4))) = t;
        }
        f16x8 fdl = *(const f16x8*)((char*)Dl + ((dv * 64 + h * 16) ^ ((dv & 3) << 4)));
        f32x4 Ov[2];
#pragma unroll
        for (int ti = 0; ti < 2; ++ti)
#pragma unroll
            for (int r = 0; r < 4; ++r)
                Ov[ti][r] = AQ[ti][r] * (ti ? R.pvb[r] : R.pva[r]);
#pragma unroll
        for (int ti = 0; ti < 2; ++ti)
            Ov[ti] = __builtin_amdgcn_mfma_f32_16x16x32_f16(R.fW[ti], fdl, Ov[ti], 0, 0, 0);
#pragma unroll
        for (int ti = 0; ti < 2; ++ti)
#pragma unroll
            for (int r = 0; r < 4; ++r) {
                long tok = (long)b * 2048 + ch * 32 + 16 * ti + 4 * h + r;
                ob[tok * 4096 + hv * 128 + vs * 16 + c] = (f16)Ov[ti][r];
            }
#pragma unroll
        for (int ti = 0; ti < 8; ++ti) {
            f16x8 fa;
#pragma unroll
            for (int e = 0; e < 8; ++e)
                fa[e] = (f16)((float)R.fkt[ti][e] * (e < 4 ? R.kwa[e] : R.kwb[e - 4]));
            int sbyte = (dv * 256 + (32 * ti + 8 * h)) ^ ((dv & 7) << 4);
            f16x4 sold = *(const f16x4*)((char*)Sl[cur] + sbyte);
            f32x4 acc;
#pragma unroll
            for (int r = 0; r < 4; ++r) acc[r] = R.pc * (float)sold[r];
            acc = __builtin_amdgcn_mfma_f32_16x16x32_f16(fa, fdl, acc, 0, 0, 0);
            f16x4 snew;
#pragma unroll
            for (int r = 0; r < 4; ++r) snew[r] = (f16)acc[r];
            *(f16x4*)((char*)Sl[cur ^ 1] + sbyte) = snew;
        }
        cur ^= 1;
        RAW_BARRIER();
    };

    CR A, B;
    loadC(A, 0);
    RAW_BARRIER();  // covers the Sl[0] zero-init ds_writes
    for (int ch = 0; ch < 64; ch += 2) {
        loadC(B, ch + 1);
        computeC(A, ch);
        loadC(A, ch + 2 < 64 ? ch + 2 : 63);
        computeC(B, ch + 1);
    }
}

// ------------------------------------------------------------------
// y = rmsnorm(o * silu(z)) * norm_w  -> f16  (vectorized f16x8)
// ------------------------------------------------------------------
__global__ __launch_bounds__(256) void gate_kernel(const f16* __restrict__ o,
                                                   const f16* __restrict__ qkvz,
                                                   const float* __restrict__ norm_w,
                                                   f16* __restrict__ y) {
    int token = blockIdx.x;  // b*2048 + s
    int tid = threadIdx.x;
    int hv = tid >> 3, part = tid & 7;
    int dv0 = part * 16;
    const f16* orow = o + ((long)token * 32 + hv) * 128 + dv0;
    long zcol = (long)(hv >> 1) * 768 + 512 + (hv & 1) * 128 + dv0;
    const f16* zrow = qkvz + (long)token * 12288 + zcol;
    f16x8 ov0 = *(const f16x8*)orow, ov1 = *(const f16x8*)(orow + 8);
    f16x8 zv0 = *(const f16x8*)zrow, zv1 = *(const f16x8*)(zrow + 8);
    float yv[16];
    float ss = 0.f;
#pragma unroll
    for (int i = 0; i < 16; ++i) {
        float ovf = (float)(i < 8 ? ov0[i] : ov1[i - 8]);
        float zvf = (float)(i < 8 ? zv0[i] : zv1[i - 8]);
        float gt = zvf / (1.f + expf(-zvf));
        float v = ovf * gt;
        yv[i] = v;
        ss += v * v;
    }
    ss += __shfl_xor(ss, 1); ss += __shfl_xor(ss, 2); ss += __shfl_xor(ss, 4);
    float scale = rsqrtf(ss * (1.f / 128.f) + 1e-6f);
    f16* yrow = y + (long)token * 4096 + hv * 128 + dv0;
    f16x8 y0, y1;
#pragma unroll
    for (int i = 0; i < 8; ++i) {
        y0[i] = (f16)(yv[i] * scale * norm_w[dv0 + i]);
        y1[i] = (f16)(yv[8 + i] * scale * norm_w[dv0 + 8 + i]);
    }
    *(f16x8*)yrow = y0;
    *(f16x8*)(yrow + 8) = y1;
}

// ------------------------------------------------------------------
// Workspace (242 MB, time-aliased) — lifetime-audited:
//   [0,96)    qkvz16  (gemm1 -> gate)
//   [96,128)  d0g (chunk_pre -> scan)         [x16 removed: cvt fused]
//   [112,160) WT (transpose -> gemm1); then Wg/T2ng/khT after gemm1
//   [128,136) Wg ; [136,144) T2ng ; [144,160) khT
//   [160,176) WTo (transpose -> gemm2)
//   [176,208) qh,kh (conv -> scan); y16 over it after scan
//   [208,240) vh (conv -> chunk_pre); ob over it (scan -> gate)
//   [240,240.5) gbuf ; [240.5,241) btb ; [241,242) pvg
// ------------------------------------------------------------------
extern "C" void kernel_launch(void* const* d_in, const int* in_sizes, int n_in,
                              void* d_out, int out_size, void* d_ws, size_t ws_size,
                              hipStream_t stream) {
    const float* x       = (const float*)d_in[0];
    const float* w_qkvz  = (const float*)d_in[1];
    const float* w_ba    = (const float*)d_in[2];
    const float* conv_w  = (const float*)d_in[3];
    const float* conv_b  = (const float*)d_in[4];
    const float* a_log   = (const float*)d_in[5];
    const float* dt_bias = (const float*)d_in[6];
    const float* norm_w  = (const float*)d_in[7];
    const float* w_o     = (const float*)d_in[8];
    float* out = (float*)d_out;

    char* ws = (char*)d_ws;
    const size_t MB = 1024 * 1024;
    f16*   qkvz16 = (f16*)ws;
    f16*   WT     = (f16*)(ws + 112 * MB);
    f16*   d0g    = (f16*)(ws + 96 * MB);
    f16*   Wg     = (f16*)(ws + 128 * MB);
    f16*   T2ng   = (f16*)(ws + 136 * MB);
    f16*   khT    = (f16*)(ws + 144 * MB);
    f16*   WTo    = (f16*)(ws + 160 * MB);
    f16*   qh     = (f16*)(ws + 176 * MB);
    f16*   kh     = (f16*)(ws + 192 * MB);
    f16*   vh     = (f16*)(ws + 208 * MB);
    f16*   ob     = (f16*)(ws + 208 * MB);
    f16*   y16    = (f16*)(ws + 176 * MB);
    float* gbuf   = (float*)(ws + 240 * MB);
    float* btb    = (float*)(ws + 240 * MB + 512 * 1024);
    float* pvg    = (float*)(ws + 241 * MB);

    // prep (cvt16 removed — fused into gemm1's A-staging)
    transpose16_kernel<<<dim3(12288 / 64, 2048 / 64), 256, 0, stream>>>(w_qkvz, WT, 2048, 12288);
    transpose16_kernel<<<dim3(2048 / 64, 4096 / 64), 256, 0, stream>>>(w_o, WTo, 4096, 2048);

    // qkvz = x @ w_qkvz  (256x256 deep-pipelined; A=fp32, cvt fused)
    gemm256_kernel<4, 1, 1><<<dim3(12288 / 256, 4096 / 256), 512, 0, stream>>>(x, WT, qkvz16, 4096, 12288, 2048);
    // ba = x @ w_ba  (fused g/beta epilogue, 4 blocks/CU)
    ba_gemm_kernel<<<1024, 256, 0, stream>>>(x, w_ba, a_log, dt_bias, gbuf, btb);

    // conv + silu + l2norm (+ fused khT transpose for k-heads)
    conv_kernel<<<dim3(64, 64, 2), 256, 0, stream>>>(qkvz16, conv_w, conv_b, qh, kh, vh, khT);
    // per-chunk UT-transform precompute
    chunk_pre_kernel<<<4096, 64, 0, stream>>>(qh, kh, vh, gbuf, btb, Wg, T2ng, d0g, pvg);
    // sequential chunked MFMA scan (register double-buffered chunk loads)
    scan_kernel<<<512, 64, 0, stream>>>(qh, kh, khT, Wg, T2ng, d0g, pvg, ob);

    // gating + rmsnorm -> y16
    gate_kernel<<<4096, 256, 0, stream>>>(ob, qkvz16, norm_w, y16);

    // out = y @ w_o  (256x128 deep-pipelined, f16 A, f32 out)
    gemm256_kernel<2, 0, 0><<<dim3(2048 / 128, 4096 / 256), 512, 0, stream>>>(y16, WTo, out, 4096, 2048, 4096);
}

// Round 21
// 693.410 us; speedup vs baseline: 1.0835x; 1.0835x over previous
//
#include <hip/hip_runtime.h>

typedef _Float16 f16;
typedef _Float16 f16x2 __attribute__((ext_vector_type(2)));
typedef _Float16 f16x4 __attribute__((ext_vector_type(4)));
typedef _Float16 f16x8 __attribute__((ext_vector_type(8)));
typedef float f32x4 __attribute__((ext_vector_type(4)));

#define QSCALE 0.08838834764831845f  // DK^-0.5

#define RAW_BARRIER() do { \
    asm volatile("s_waitcnt lgkmcnt(0)" ::: "memory"); \
    __builtin_amdgcn_s_barrier(); \
    __builtin_amdgcn_sched_barrier(0); \
} while (0)

// ------------------------------------------------------------------
// convert fp32 -> f16 (vectorized x4)
// ------------------------------------------------------------------
__global__ __launch_bounds__(256) void cvt16_kernel(const float* __restrict__ in,
                                                    f16* __restrict__ out, int n4) {
    int i = blockIdx.x * 256 + threadIdx.x;
    if (i >= n4) return;
    f32x4 v = ((const f32x4*)in)[i];
    f16x4 h;
    h[0] = (f16)v[0]; h[1] = (f16)v[1]; h[2] = (f16)v[2]; h[3] = (f16)v[3];
    ((f16x4*)out)[i] = h;
}

// ------------------------------------------------------------------
// transpose fp32 [R][C] -> f16 [C][R]
// ------------------------------------------------------------------
__global__ __launch_bounds__(256) void transpose16_kernel(const float* __restrict__ in,
                                                          f16* __restrict__ out, int R, int C) {
    __shared__ f16 tile[64][66];
    int c0 = blockIdx.x * 64, r0 = blockIdx.y * 64;
    int tid = threadIdx.x;
#pragma unroll
    for (int i = 0; i < 16; ++i) {
        int idx = i * 256 + tid;
        int r = idx >> 6, c = idx & 63;
        tile[r][c] = (f16)in[(long)(r0 + r) * C + (c0 + c)];
    }
    __syncthreads();
#pragma unroll
    for (int i = 0; i < 16; ++i) {
        int idx = i * 256 + tid;
        int orow = idx >> 6, oc = idx & 63;
        out[(long)(c0 + orow) * R + (r0 + oc)] = tile[oc][orow];
    }
}

// ------------------------------------------------------------------
// 256xBN deep-pipelined f16 MFMA GEMM. BN = 64*NJ.
// r16 schedule (measured best): monolithic MFMA phase, commit-before-
// MFMA, 2-ahead reg prefetch, raw barriers with lgkmcnt-only drain
// (global loads stay in flight), setprio on MFMA.
// ------------------------------------------------------------------
template <int NJ, int F16OUT>
__global__ __launch_bounds__(512, 1) void gemm256_kernel(const f16* __restrict__ A,
                                                         const f16* __restrict__ Bt,
                                                         void* __restrict__ Cout,
                                                         int M, int N, int Kd) {
    constexpr int BN = 64 * NJ;
    constexpr int BNW = 16 * NJ;
    __shared__ f16 sA[2][256 * 64];
    __shared__ f16 sB[2][BN * 64];
    const int tid = threadIdx.x;
    const int lane = tid & 63, wv = tid >> 6;
    const int wm = wv >> 2, wn = wv & 3;
    const int m0 = blockIdx.y * 256, n0 = blockIdx.x * BN;
    const int lrow = lane & 15, lk = lane >> 4;
    const int nK = Kd >> 6;

    f32x4 acc[8][NJ] = {};
    f32x4 ra[4], rb[NJ];

    auto issue = [&](int k0) {
#pragma unroll
        for (int j = 0; j < 4; ++j) {
            int P = (tid + j * 512) * 16;
            int row = P >> 7;
            int koff = (P & 127) >> 1;
            ra[j] = *(const f32x4*)(A + (long)(m0 + row) * Kd + k0 + koff);
        }
#pragma unroll
        for (int j = 0; j < NJ; ++j) {
            int P = (tid + j * 512) * 16;
            int row = P >> 7;
            int koff = (P & 127) >> 1;
            rb[j] = *(const f32x4*)(Bt + (long)(n0 + row) * Kd + k0 + koff);
        }
    };
    auto commit = [&](int buf) {
#pragma unroll
        for (int j = 0; j < 4; ++j) {
            int P = (tid + j * 512) * 16;
            int row = P >> 7;
            int sw = P ^ ((row & 7) << 4);
            *(f32x4*)((char*)&sA[buf][0] + sw) = ra[j];
        }
#pragma unroll
        for (int j = 0; j < NJ; ++j) {
            int P = (tid + j * 512) * 16;
            int row = P >> 7;
            int sw = P ^ ((row & 7) << 4);
            *(f32x4*)((char*)&sB[buf][0] + sw) = rb[j];
        }
    };

    issue(0);
    commit(0);
    if (nK > 1) issue(64);
    RAW_BARRIER();

    int cur = 0;
    for (int t = 0; t < nK; ++t) {
        if (t + 1 < nK) commit(cur ^ 1);
        if (t + 2 < nK) issue((t + 2) * 64);
        const char* bA = (const char*)&sA[cur][0];
        const char* bB = (const char*)&sB[cur][0];
        __builtin_amdgcn_s_setprio(1);
#pragma unroll
        for (int kk = 0; kk < 2; ++kk) {
            f16x8 bf[NJ];
#pragma unroll
            for (int j = 0; j < NJ; ++j) {
                int brow = wn * BNW + j * 16 + lrow;
                int bbyte = brow * 128 + kk * 64 + lk * 16;
                bf[j] = *(const f16x8*)(bB + (bbyte ^ ((brow & 7) << 4)));
            }
#pragma unroll
            for (int i = 0; i < 8; ++i) {
                int arow = wm * 128 + i * 16 + lrow;
                int abyte = arow * 128 + kk * 64 + lk * 16;
                f16x8 af = *(const f16x8*)(bA + (abyte ^ ((arow & 7) << 4)));
#pragma unroll
                for (int j = 0; j < NJ; ++j)
                    acc[i][j] = __builtin_amdgcn_mfma_f32_16x16x32_f16(af, bf[j], acc[i][j], 0, 0, 0);
            }
        }
        __builtin_amdgcn_s_setprio(0);
        RAW_BARRIER();
        cur ^= 1;
    }

#pragma unroll
    for (int i = 0; i < 8; ++i) {
        int gm_base = m0 + wm * 128 + i * 16 + lk * 4;
#pragma unroll
        for (int j = 0; j < NJ; ++j) {
            int gn = n0 + wn * BNW + j * 16 + lrow;
#pragma unroll
            for (int r = 0; r < 4; ++r) {
                long idx = (long)(gm_base + r) * N + gn;
                if (F16OUT) ((f16*)Cout)[idx] = (f16)acc[i][j][r];
                else        ((float*)Cout)[idx] = acc[i][j][r];
            }
        }
    }
}

// ------------------------------------------------------------------
// ba = x @ w_ba, FUSED g/beta epilogue (r17, 4 blocks/CU — proven).
// ------------------------------------------------------------------
__global__ __launch_bounds__(256) void ba_gemm_kernel(const float* __restrict__ x,
                                                      const float* __restrict__ w,
                                                      const float* __restrict__ a_log,
                                                      const float* __restrict__ dt_bias,
                                                      float* __restrict__ gout,
                                                      float* __restrict__ bt) {
    __shared__ float xs[4][2048];
    int tid = threadIdx.x;
    int t0 = blockIdx.x * 4;
    int o = tid & 63, tg = tid >> 6;
    for (int i = tid; i < 4 * 512; i += 256) {
        int tok = i >> 9, kq = i & 511;
        ((f32x4*)&xs[tok][0])[kq] = ((const f32x4*)(x + (long)(t0 + tok) * 2048))[kq];
    }
    __syncthreads();
    const float* xr = &xs[tg][0];
    float acc = 0.f;
    for (int k = 0; k < 2048; ++k)
        acc = fmaf(xr[k], w[(long)k * 64 + o], acc);

    int hv = ((o >> 2) << 1) | (o & 1);
    bool isB = (o & 2) == 0;
    int tok = t0 + tg;
    int b = tok >> 11, s = tok & 2047;
    long oidx = ((long)b * 32 + hv) * 2048 + s;
    if (isB) {
        bt[oidx] = 1.f / (1.f + expf(-acc));
    } else {
        float xx = acc + dt_bias[hv];
        float sp = (xx > 20.f) ? xx : log1pf(expf(xx));
        gout[oidx] = -expf(a_log[hv]) * sp;
    }
}

// ------------------------------------------------------------------
// depthwise causal conv(K=4) + bias + SiLU (+ L2norm for q/k heads)
// k-head blocks ALSO emit the transposed copy khT.
// ------------------------------------------------------------------
__global__ __launch_bounds__(256) void conv_kernel(const f16* __restrict__ qkvz,
                                                   const float* __restrict__ cw,
                                                   const float* __restrict__ cb,
                                                   f16* __restrict__ qh,
                                                   f16* __restrict__ kh,
                                                   f16* __restrict__ vh,
                                                   f16* __restrict__ khT) {
    __shared__ float Lin[35 * 128];
    __shared__ float Lout[32 * 128];
    __shared__ float Lsc[32];
    int g = blockIdx.x;
    int s0 = blockIdx.y * 32;
    int b = blockIdx.z;
    int tid = threadIdx.x;
    int colbase, chbase;
    f16* outp;
    bool donorm;
    bool isk = false;
    int hk = 0;
    float nmul;
    if (g < 16) {
        colbase = g * 768; chbase = g * 128;
        outp = qh + (((long)b * 16 + g) * 2048 + s0) * 128;
        donorm = true; nmul = QSCALE;
    } else if (g < 32) {
        hk = g - 16;
        colbase = hk * 768 + 128; chbase = 2048 + hk * 128;
        outp = kh + (((long)b * 16 + hk) * 2048 + s0) * 128;
        donorm = true; nmul = 1.f; isk = true;
    } else {
        int hv = g - 32;
        colbase = (hv >> 1) * 768 + 256 + (hv & 1) * 128; chbase = 4096 + hv * 128;
        outp = vh + (((long)b * 32 + hv) * 2048 + s0) * 128;
        donorm = false; nmul = 1.f;
    }
    for (int ci = tid; ci < 35 * 16; ci += 256) {
        int sr = ci >> 4, cc = (ci & 15) * 8;
        int s = s0 + sr - 3;
        f32x4 lo = {}, hi = {};
        if (s >= 0) {
            f16x8 v = *(const f16x8*)(qkvz + ((long)b * 2048 + s) * 12288 + colbase + cc);
#pragma unroll
            for (int e = 0; e < 4; ++e) { lo[e] = (float)v[e]; hi[e] = (float)v[4 + e]; }
        }
        *(f32x4*)&Lin[sr * 128 + cc] = lo;
        *(f32x4*)&Lin[sr * 128 + cc + 4] = hi;
    }
    __syncthreads();
    int c = tid & 127, sg = tid >> 7;
    float w0 = cw[(chbase + c) * 4 + 0];
    float w1 = cw[(chbase + c) * 4 + 1];
    float w2 = cw[(chbase + c) * 4 + 2];
    float w3 = cw[(chbase + c) * 4 + 3];
    float bias = cb[chbase + c];
#pragma unroll
    for (int j = 0; j < 16; ++j) {
        int sl = sg * 16 + j;
        float v = w0 * Lin[sl * 128 + c] + w1 * Lin[(sl + 1) * 128 + c] +
                  w2 * Lin[(sl + 2) * 128 + c] + w3 * Lin[(sl + 3) * 128 + c] + bias;
        v = v / (1.f + expf(-v));  // SiLU
        Lout[sl * 128 + c] = v;
    }
    __syncthreads();
    if (donorm) {
        int token = tid >> 3, part = tid & 7;
        float ss = 0.f;
#pragma unroll
        for (int i = 0; i < 16; ++i) {
            float v = Lout[token * 128 + part * 16 + i];
            ss += v * v;
        }
        ss += __shfl_xor(ss, 1); ss += __shfl_xor(ss, 2); ss += __shfl_xor(ss, 4);
        if (part == 0) Lsc[token] = rsqrtf(ss + 1e-6f) * nmul;
        __syncthreads();
#pragma unroll
        for (int j = 0; j < 16; ++j) {
            int sl = sg * 16 + j;
            outp[(long)sl * 128 + c] = (f16)(Lout[sl * 128 + c] * Lsc[sl]);
        }
        if (isk) {
            int dk = tid >> 1, sh = tid & 1;
            f16x8 v0, v1;
#pragma unroll
            for (int i = 0; i < 8; ++i) {
                v0[i] = (f16)(Lout[(sh * 16 + i) * 128 + dk] * Lsc[sh * 16 + i]);
                v1[i] = (f16)(Lout[(sh * 16 + 8 + i) * 128 + dk] * Lsc[sh * 16 + 8 + i]);
            }
            f16* kt = khT + ((long)(b * 16 + hk) * 128 + dk) * 2048 + s0 + sh * 16;
            *(f16x8*)kt = v0;
            *(f16x8*)(kt + 8) = v1;
        }
    } else {
#pragma unroll
        for (int j = 0; j < 16; ++j) {
            int sl = sg * 16 + j;
            outp[(long)sl * 128 + c] = (f16)Lout[sl * 128 + c];
        }
    }
}

// ------------------------------------------------------------------
// chunk_pre: per (b,hv,chunk of 32) — one wave. (r15/r17, proven)
// ------------------------------------------------------------------
__global__ __launch_bounds__(64) void chunk_pre_kernel(const f16* __restrict__ qh,
                                                       const f16* __restrict__ kh,
                                                       const f16* __restrict__ vh,
                                                       const float* __restrict__ gb,
                                                       const float* __restrict__ bt,
                                                       f16* __restrict__ Wg,
                                                       f16* __restrict__ T2ng,
                                                       f16* __restrict__ d0g,
                                                       float* __restrict__ pvg) {
    __shared__ f16 VTl[128 * 32];
    __shared__ float KKl[32 * 32];
    __shared__ float RL[32 * 32];
    __shared__ float Tf[32 * 33];
    __shared__ f16 Tl[32 * 64];
    __shared__ float cuml[32], bl[32], pl[32];

    int bid = blockIdx.x;
    int chunk = bid & 63;
    int hv = (bid >> 6) & 31;
    int b = bid >> 11;
    int bh = b * 16 + (hv >> 1);
    int l = threadIdx.x;
    int h = l >> 4, c = l & 15;
    long chid = bid;

    const f16* kbase = kh + ((long)bh * 2048 + chunk * 32) * 128;
    const f16* qbase = qh + ((long)bh * 2048 + chunk * 32) * 128;
    const f16* vbase = vh + (((long)b * 32 + hv) * 2048 + chunk * 32) * 128;
    const float* gp = gb + ((long)b * 32 + hv) * 2048 + chunk * 32;
    const float* bp = bt + ((long)b * 32 + hv) * 2048 + chunk * 32;

    f16x8 fk[2][4], fq[2][4];
#pragma unroll
    for (int ti = 0; ti < 2; ++ti)
#pragma unroll
        for (int kk = 0; kk < 4; ++kk) {
            fk[ti][kk] = *(const f16x8*)(kbase + (c + 16 * ti) * 128 + kk * 32 + h * 8);
            fq[ti][kk] = *(const f16x8*)(qbase + (c + 16 * ti) * 128 + kk * 32 + h * 8);
        }

    float gv = (l < 32) ? gp[l] : 0.f;
#pragma unroll
    for (int d = 1; d < 32; d <<= 1) {
        float t2 = __shfl_up(gv, d);
        if (l >= d) gv += t2;
    }
    if (l < 32) { cuml[l] = gv; bl[l] = bp[l]; pl[l] = expf(gv); }
    __syncthreads();

#pragma unroll
    for (int it = 0; it < 8; ++it) {
        int idx = (l + it * 64) * 8;
        int row = idx >> 7, col = idx & 127;
        f16x8 v = *(const f16x8*)(vbase + (long)row * 128 + col);
        float be = bl[row];
#pragma unroll
        for (int e = 0; e < 8; ++e) {
            int dv = col + e;
            int byte = (dv * 64 + row * 2) ^ ((dv & 3) << 4);
            *(f16*)((char*)VTl + byte) = (f16)((float)v[e] * be);
        }
    }
#pragma unroll
    for (int it = 0; it < 16; ++it) {
        int e = l * 16 + it;
        int i = e >> 5, j = e & 31;
        RL[e] = (j <= i) ? expf(cuml[i] - cuml[j]) : 0.f;
    }
    __syncthreads();

    {
        f32x4 acc[2][2] = {};
#pragma unroll
        for (int kk = 0; kk < 4; ++kk) {
            acc[0][0] = __builtin_amdgcn_mfma_f32_16x16x32_f16(fk[0][kk], fk[0][kk], acc[0][0], 0, 0, 0);
            acc[0][1] = __builtin_amdgcn_mfma_f32_16x16x32_f16(fk[0][kk], fk[1][kk], acc[0][1], 0, 0, 0);
            acc[1][0] = __builtin_amdgcn_mfma_f32_16x16x32_f16(fk[1][kk], fk[0][kk], acc[1][0], 0, 0, 0);
            acc[1][1] = __builtin_amdgcn_mfma_f32_16x16x32_f16(fk[1][kk], fk[1][kk], acc[1][1], 0, 0, 0);
        }
#pragma unroll
        for (int ti = 0; ti < 2; ++ti)
#pragma unroll
            for (int tj = 0; tj < 2; ++tj)
#pragma unroll
                for (int r = 0; r < 4; ++r)
                    KKl[(h * 4 + r + 16 * ti) * 32 + c + 16 * tj] = acc[ti][tj][r];
    }
    {
        f32x4 acc[2][2] = {};
#pragma unroll
        for (int kk = 0; kk < 4; ++kk) {
            acc[0][0] = __builtin_amdgcn_mfma_f32_16x16x32_f16(fq[0][kk], fk[0][kk], acc[0][0], 0, 0, 0);
            acc[0][1] = __builtin_amdgcn_mfma_f32_16x16x32_f16(fq[0][kk], fk[1][kk], acc[0][1], 0, 0, 0);
            acc[1][0] = __builtin_amdgcn_mfma_f32_16x16x32_f16(fq[1][kk], fk[0][kk], acc[1][0], 0, 0, 0);
            acc[1][1] = __builtin_amdgcn_mfma_f32_16x16x32_f16(fq[1][kk], fk[1][kk], acc[1][1], 0, 0, 0);
        }
        __syncthreads();
#pragma unroll
        for (int ti = 0; ti < 2; ++ti)
#pragma unroll
            for (int tj = 0; tj < 2; ++tj)
#pragma unroll
                for (int r = 0; r < 4; ++r) {
                    int i = h * 4 + r + 16 * ti, j = c + 16 * tj;
                    Wg[chid * 1024 + i * 32 + j] = (f16)(acc[ti][tj][r] * RL[i * 32 + j]);
                }
    }

    if (l < 32) {
        int j = l;
        for (int i = 0; i < 32; ++i) {
            float s = (i == j) ? 1.f : 0.f;
            float bi = bl[i];
            for (int ll = j; ll < i; ++ll)
                s -= bi * KKl[i * 32 + ll] * RL[i * 32 + ll] * Tf[ll * 33 + j];
            Tf[i * 33 + j] = s;
        }
        float bpj = bl[j] * pl[j];
        for (int i = 0; i < 32; ++i) {
            float tv = (i >= j) ? Tf[i * 33 + j] : 0.f;
            int byte = (i * 128 + j * 2) ^ ((i & 3) << 4);
            *(f16*)((char*)Tl + byte) = (f16)tv;
            T2ng[chid * 1024 + i * 32 + j] = (f16)(-tv * bpj);
        }
        pvg[chid * 64 + j] = pl[j];
        pvg[chid * 64 + 32 + j] = expf(cuml[31] - cuml[j]);
    }
    __syncthreads();

    {
        f16x8 fT[2];
#pragma unroll
        for (int ti = 0; ti < 2; ++ti) {
            int row = c + 16 * ti;
            fT[ti] = *(const f16x8*)((const char*)Tl + ((row * 128 + h * 16) ^ ((row & 3) << 4)));
        }
#pragma unroll
        for (int nj = 0; nj < 8; ++nj) {
            int dv = c + 16 * nj;
            f16x8 fv = *(const f16x8*)((const char*)VTl + ((dv * 64 + h * 16) ^ ((dv & 3) << 4)));
            f32x4 a0 = {}, a1 = {};
            a0 = __builtin_amdgcn_mfma_f32_16x16x32_f16(fT[0], fv, a0, 0, 0, 0);
            a1 = __builtin_amdgcn_mfma_f32_16x16x32_f16(fT[1], fv, a1, 0, 0, 0);
            f16x4 s0, s1;
#pragma unroll
            for (int r = 0; r < 4; ++r) { s0[r] = (f16)a0[r]; s1[r] = (f16)a1[r]; }
            *(f16x4*)(d0g + chid * 4096 + (long)dv * 32 + 4 * h) = s0;
            *(f16x4*)(d0g + chid * 4096 + (long)dv * 32 + 16 + 4 * h) = s1;
        }
    }
}

// ------------------------------------------------------------------
// sequential chunked scan: grid 512 = (b,hv,vs of 16 dv); 1 wave.
// 2-chunk register double-buffer (r16, proven).
// ------------------------------------------------------------------
struct CR {
    f16x8 fk[2][4], fq[2][4], fkt[8], fT[2], fW[2];
    f16x4 fd0[2];
    f32x4 pva, pvb, kwa, kwb;
    float pc;
};

__global__ __launch_bounds__(64, 1) void scan_kernel(const f16* __restrict__ qh,
                                                     const f16* __restrict__ kh,
                                                     const f16* __restrict__ khT,
                                                     const f16* __restrict__ Wg,
                                                     const f16* __restrict__ T2ng,
                                                     const f16* __restrict__ d0g,
                                                     const float* __restrict__ pvg,
                                                     f16* __restrict__ ob) {
    __shared__ f16 Sl[2][16 * 128];
    __shared__ f16 AKl[16 * 32];
    __shared__ f16 Dl[16 * 32];

    int pbid = blockIdx.x;
    int bid = (pbid & 7) * 64 + (pbid >> 3);
    int vs = bid & 7;
    int hv = (bid >> 3) & 31;
    int b = bid >> 8;
    int bh32 = b * 32 + hv;
    int bh = b * 16 + (hv >> 1);
    int l = threadIdx.x, h = l >> 4, c = l & 15;

    const f16* kb = kh + (long)bh * 2048 * 128;
    const f16* qb = qh + (long)bh * 2048 * 128;
    const f16* ktb = khT + (long)bh * 128 * 2048;

    f16x8 z = {};
#pragma unroll
    for (int it = 0; it < 4; ++it) *(f16x8*)((char*)Sl[0] + (l + it * 64) * 16) = z;

    int cur = 0;

    auto loadC = [&](CR& R, int ch) {
        long chid = (long)bh32 * 64 + ch;
#pragma unroll
        for (int ti = 0; ti < 2; ++ti) {
            long row = (long)ch * 32 + c + 16 * ti;
#pragma unroll
            for (int kk = 0; kk < 4; ++kk) {
                R.fk[ti][kk] = *(const f16x8*)(kb + row * 128 + kk * 32 + h * 8);
                R.fq[ti][kk] = *(const f16x8*)(qb + row * 128 + kk * 32 + h * 8);
            }
            R.fT[ti] = *(const f16x8*)(T2ng + chid * 1024 + (c + 16 * ti) * 32 + h * 8);
            R.fW[ti] = *(const f16x8*)(Wg + chid * 1024 + (c + 16 * ti) * 32 + h * 8);
        }
#pragma unroll
        for (int ti = 0; ti < 8; ++ti)
            R.fkt[ti] = *(const f16x8*)(ktb + (long)(c + 16 * ti) * 2048 + ch * 32 + h * 8);
#pragma unroll
        for (int ti = 0; ti < 2; ++ti)
            R.fd0[ti] = *(const f16x4*)(d0g + chid * 4096 +
                                        (long)(vs * 16 + c) * 32 + 16 * ti + 4 * h);
        R.pva = *(const f32x4*)(pvg + chid * 64 + 4 * h);
        R.pvb = *(const f32x4*)(pvg + chid * 64 + 16 + 4 * h);
        R.pc = pvg[chid * 64 + 31];
        R.kwa = *(const f32x4*)(pvg + chid * 64 + 32 + h * 8);
        R.kwb = *(const f32x4*)(pvg + chid * 64 + 36 + h * 8);
    };

    auto computeC = [&](const CR& R, int ch) {
        const int dv = c;
        f16x8 fS[4];
#pragma unroll
        for (int kk = 0; kk < 4; ++kk)
            fS[kk] = *(const f16x8*)((char*)Sl[cur] +
                                     (dv * 256 + ((kk * 64 + h * 16) ^ ((dv & 7) << 4))));
        f32x4 AK[2] = {}, AQ[2] = {};
#pragma unroll
        for (int ti = 0; ti < 2; ++ti)
#pragma unroll
            for (int kk = 0; kk < 4; ++kk) {
                AK[ti] = __builtin_amdgcn_mfma_f32_16x16x32_f16(R.fk[ti][kk], fS[kk], AK[ti], 0, 0, 0);
                AQ[ti] = __builtin_amdgcn_mfma_f32_16x16x32_f16(R.fq[ti][kk], fS[kk], AQ[ti], 0, 0, 0);
            }
#pragma unroll
        for (int ti = 0; ti < 2; ++ti) {
            f16x4 t;
#pragma unroll
            for (int r = 0; r < 4; ++r) t[r] = (f16)AK[ti][r];
            *(f16x4*)((char*)AKl + ((dv * 64 + 32 * ti + 8 * h) ^ ((dv & 3) << 4))) = t;
        }
        f32x4 Dv[2];
#pragma unroll
        for (int ti = 0; ti < 2; ++ti)
#pragma unroll
            for (int r = 0; r < 4; ++r) Dv[ti][r] = (float)R.fd0[ti][r];
        {
            f16x8 fak = *(const f16x8*)((char*)AKl + ((dv * 64 + h * 16) ^ ((dv & 3) << 4)));
#pragma unroll
            for (int ti = 0; ti < 2; ++ti)
                Dv[ti] = __builtin_amdgcn_mfma_f32_16x16x32_f16(R.fT[ti], fak, Dv[ti], 0, 0, 0);
        }
#pragma unroll
        for (int ti = 0; ti < 2; ++ti) {
            f16x4 t;
#pragma unroll
            for (int r = 0; r < 4; ++r) t[r] = (f16)Dv[ti][r];
            *(f16x4*)((char*)Dl + ((dv * 64 + 32 * ti + 8 * h) ^ ((dv & 3) << 4))) = t;
        }
        f16x8 fdl = *(const f16x8*)((char*)Dl + ((dv * 64 + h * 16) ^ ((dv & 3) << 4)));
        f32x4 Ov[2];
#pragma unroll
        for (int ti = 0; ti < 2; ++ti)
#pragma unroll
            for (int r = 0; r < 4; ++r)
                Ov[ti][r] = AQ[ti][r] * (ti ? R.pvb[r] : R.pva[r]);
#pragma unroll
        for (int ti = 0; ti < 2; ++ti)
            Ov[ti] = __builtin_amdgcn_mfma_f32_16x16x32_f16(R.fW[ti], fdl, Ov[ti], 0, 0, 0);
#pragma unroll
        for (int ti = 0; ti < 2; ++ti)
#pragma unroll
            for (int r = 0; r < 4; ++r) {
                long tok = (long)b * 2048 + ch * 32 + 16 * ti + 4 * h + r;
                ob[tok * 4096 + hv * 128 + vs * 16 + c] = (f16)Ov[ti][r];
            }
#pragma unroll
        for (int ti = 0; ti < 8; ++ti) {
            f16x8 fa;
#pragma unroll
            for (int e = 0; e < 8; ++e)
                fa[e] = (f16)((float)R.fkt[ti][e] * (e < 4 ? R.kwa[e] : R.kwb[e - 4]));
            int sbyte = (dv * 256 + (32 * ti + 8 * h)) ^ ((dv & 7) << 4);
            f16x4 sold = *(const f16x4*)((char*)Sl[cur] + sbyte);
            f32x4 acc;
#pragma unroll
            for (int r = 0; r < 4; ++r) acc[r] = R.pc * (float)sold[r];
            acc = __builtin_amdgcn_mfma_f32_16x16x32_f16(fa, fdl, acc, 0, 0, 0);
            f16x4 snew;
#pragma unroll
            for (int r = 0; r < 4; ++r) snew[r] = (f16)acc[r];
            *(f16x4*)((char*)Sl[cur ^ 1] + sbyte) = snew;
        }
        cur ^= 1;
        RAW_BARRIER();
    };

    CR A, B;
    loadC(A, 0);
    RAW_BARRIER();  // covers the Sl[0] zero-init ds_writes
    for (int ch = 0; ch < 64; ch += 2) {
        loadC(B, ch + 1);
        computeC(A, ch);
        loadC(A, ch + 2 < 64 ? ch + 2 : 63);
        computeC(B, ch + 1);
    }
}

// ------------------------------------------------------------------
// y = rmsnorm(o * silu(z)) * norm_w  -> f16  (vectorized f16x8)
// ------------------------------------------------------------------
__global__ __launch_bounds__(256) void gate_kernel(const f16* __restrict__ o,
                                                   const f16* __restrict__ qkvz,
                                                   const float* __restrict__ norm_w,
                                                   f16* __restrict__ y) {
    int token = blockIdx.x;  // b*2048 + s
    int tid = threadIdx.x;
    int hv = tid >> 3, part = tid & 7;
    int dv0 = part * 16;
    const f16* orow = o + ((long)token * 32 + hv) * 128 + dv0;
    long zcol = (long)(hv >> 1) * 768 + 512 + (hv & 1) * 128 + dv0;
    const f16* zrow = qkvz + (long)token * 12288 + zcol;
    f16x8 ov0 = *(const f16x8*)orow, ov1 = *(const f16x8*)(orow + 8);
    f16x8 zv0 = *(const f16x8*)zrow, zv1 = *(const f16x8*)(zrow + 8);
    float yv[16];
    float ss = 0.f;
#pragma unroll
    for (int i = 0; i < 16; ++i) {
        float ovf = (float)(i < 8 ? ov0[i] : ov1[i - 8]);
        float zvf = (float)(i < 8 ? zv0[i] : zv1[i - 8]);
        float gt = zvf / (1.f + expf(-zvf));
        float v = ovf * gt;
        yv[i] = v;
        ss += v * v;
    }
    ss += __shfl_xor(ss, 1); ss += __shfl_xor(ss, 2); ss += __shfl_xor(ss, 4);
    float scale = rsqrtf(ss * (1.f / 128.f) + 1e-6f);
    f16* yrow = y + (long)token * 4096 + hv * 128 + dv0;
    f16x8 y0, y1;
#pragma unroll
    for (int i = 0; i < 8; ++i) {
        y0[i] = (f16)(yv[i] * scale * norm_w[dv0 + i]);
        y1[i] = (f16)(yv[8 + i] * scale * norm_w[dv0 + 8 + i]);
    }
    *(f16x8*)yrow = y0;
    *(f16x8*)(yrow + 8) = y1;
}

// ------------------------------------------------------------------
// Workspace (242 MB, time-aliased) — lifetime-audited (r19 layout).
// ------------------------------------------------------------------
extern "C" void kernel_launch(void* const* d_in, const int* in_sizes, int n_in,
                              void* d_out, int out_size, void* d_ws, size_t ws_size,
                              hipStream_t stream) {
    const float* x       = (const float*)d_in[0];
    const float* w_qkvz  = (const float*)d_in[1];
    const float* w_ba    = (const float*)d_in[2];
    const float* conv_w  = (const float*)d_in[3];
    const float* conv_b  = (const float*)d_in[4];
    const float* a_log   = (const float*)d_in[5];
    const float* dt_bias = (const float*)d_in[6];
    const float* norm_w  = (const float*)d_in[7];
    const float* w_o     = (const float*)d_in[8];
    float* out = (float*)d_out;

    char* ws = (char*)d_ws;
    const size_t MB = 1024 * 1024;
    f16*   qkvz16 = (f16*)ws;
    f16*   x16    = (f16*)(ws + 96 * MB);
    f16*   WT     = (f16*)(ws + 112 * MB);
    f16*   d0g    = (f16*)(ws + 96 * MB);
    f16*   Wg     = (f16*)(ws + 128 * MB);
    f16*   T2ng   = (f16*)(ws + 136 * MB);
    f16*   khT    = (f16*)(ws + 144 * MB);
    f16*   WTo    = (f16*)(ws + 160 * MB);
    f16*   qh     = (f16*)(ws + 176 * MB);
    f16*   kh     = (f16*)(ws + 192 * MB);
    f16*   vh     = (f16*)(ws + 208 * MB);
    f16*   ob     = (f16*)(ws + 208 * MB);
    f16*   y16    = (f16*)(ws + 176 * MB);
    float* gbuf   = (float*)(ws + 240 * MB);
    float* btb    = (float*)(ws + 240 * MB + 512 * 1024);
    float* pvg    = (float*)(ws + 241 * MB);

    // prep
    cvt16_kernel<<<8192, 256, 0, stream>>>(x, x16, 4096 * 2048 / 4);
    transpose16_kernel<<<dim3(12288 / 64, 2048 / 64), 256, 0, stream>>>(w_qkvz, WT, 2048, 12288);
    transpose16_kernel<<<dim3(2048 / 64, 4096 / 64), 256, 0, stream>>>(w_o, WTo, 4096, 2048);

    // qkvz = x @ w_qkvz  (256x256 deep-pipelined, r16 schedule)
    gemm256_kernel<4, 1><<<dim3(12288 / 256, 4096 / 256), 512, 0, stream>>>(x16, WT, qkvz16, 4096, 12288, 2048);
    // ba = x @ w_ba  (fused g/beta epilogue, 4 blocks/CU)
    ba_gemm_kernel<<<1024, 256, 0, stream>>>(x, w_ba, a_log, dt_bias, gbuf, btb);

    // conv + silu + l2norm (+ fused khT transpose for k-heads)
    conv_kernel<<<dim3(64, 64, 2), 256, 0, stream>>>(qkvz16, conv_w, conv_b, qh, kh, vh, khT);
    // per-chunk UT-transform precompute
    chunk_pre_kernel<<<4096, 64, 0, stream>>>(qh, kh, vh, gbuf, btb, Wg, T2ng, d0g, pvg);
    // sequential chunked MFMA scan (register double-buffered chunk loads)
    scan_kernel<<<512, 64, 0, stream>>>(qh, kh, khT, Wg, T2ng, d0g, pvg, ob);

    // gating + rmsnorm -> y16
    gate_kernel<<<4096, 256, 0, stream>>>(ob, qkvz16, norm_w, y16);

    // out = y @ w_o  (256x128 deep-pipelined, f32 out)
    gemm256_kernel<2, 0><<<dim3(2048 / 128, 4096 / 256), 512, 0, stream>>>(y16, WTo, out, 4096, 2048, 4096);
}